// Round 12
// baseline (425.768 us; speedup 1.0000x reference)
//
#include <hip/hip_runtime.h>

// GraphConv 3-hop SpMM. R12: feature-split hops over feature-major bf16
// shadow planes ([plane][node][32feat], 32MB/plane) -> gather set per pass
// is a contiguous 32MB, guaranteed L3-resident. Otherwise R11 structure:
//  - all d_out writes nontemporal; ELL(12)-direct build; fat init||scatter;
//  - overflow (deg>12) atomic fixup + shadow re-derive.
// d_out layout: [N_NODES, 4, 64] fp32.

#define DFEAT 64
#define ELLW 12

typedef float f32x4 __attribute__((ext_vector_type(4)));

__device__ inline unsigned bf16rne(float x) {           // bf16 in high 16 bits
    unsigned u = __float_as_uint(x);
    u += 0x7FFF + ((u >> 16) & 1);
    return u;
}
__device__ inline unsigned pack2(float lo, float hi) {  // [lo|hi] packed bf16x2
    return (bf16rne(lo) >> 16) | (bf16rne(hi) & 0xFFFF0000u);
}
__device__ inline float bflo(unsigned w) { return __uint_as_float(w << 16); }
__device__ inline float bfhi(unsigned w) { return __uint_as_float(w & 0xFFFF0000u); }

// ---------- zero cnt + ovfcnt ----------
__global__ void gc_zero(int4* __restrict__ p, int n4) {
    int i = blockIdx.x * blockDim.x + threadIdx.x;
    if (i < n4) p[i] = make_int4(0, 0, 0, 0);
}

// ---------- fat: blocks [0,initB) init hop0 (NT d_out + shadow planes);
//             blocks [initB,..) ELL scatter ----------
__global__ void gc_fat(const float4* __restrict__ user4,
                       const float4* __restrict__ item4,
                       float4* __restrict__ out4, char* __restrict__ shadow0,
                       const int* __restrict__ row, const int* __restrict__ col,
                       const float* __restrict__ val,
                       int* __restrict__ cnt, float2* __restrict__ ell,
                       int* __restrict__ ovfcnt, int4* __restrict__ ovf,
                       int n_users, int n_nodes, int nnz, int initB) {
    int b = blockIdx.x;
    if (b < initB) {
        int tid = b * blockDim.x + threadIdx.x;
        if (tid >= n_nodes * 16) return;
        int node = tid >> 4;
        int q = tid & 15;                      // float4-quad (4 feats) within node
        float4 v = (node < n_users) ? user4[(size_t)node * 16 + q]
                                    : item4[(size_t)(node - n_users) * 16 + q];
        f32x4 nv = {v.x, v.y, v.z, v.w};
        __builtin_nontemporal_store(nv, (f32x4*)(out4 + (size_t)node * 64 + q));
        // plane = q>>3 (feats 0-31 / 32-63); 64B per node per plane (8 uint2).
        uint2* pl = (uint2*)(shadow0 + (size_t)(q >> 3) * n_nodes * 64);
        pl[(size_t)node * 8 + (q & 7)] = make_uint2(pack2(v.x, v.y), pack2(v.z, v.w));
    } else {
        int i = (b - initB) * blockDim.x + threadIdx.x;
        if (i >= nnz) return;
        int r = row[i];
        int pos = atomicAdd(&cnt[r], 1);
        if (pos < ELLW) {
            // colcode = col*4 (int4 index within a 64B/node plane)
            ell[(size_t)r * ELLW + pos] = make_float2(__int_as_float(col[i] << 2), val[i]);
        } else {
            int o = atomicAdd(ovfcnt, 1);
            ovf[o] = make_int4(r, col[i] << 6, __float_as_int(val[i]), 0);
        }
    }
}

// ---------- hop half-pass: 4 lanes/row (8 bf16 feats each), 16 rows/wave ----------
__global__ void gc_hop(const int* __restrict__ cnt,
                       const float4* __restrict__ ell4,     // 2 slots per float4
                       const int4* __restrict__ ssrc,       // bf16 plane source
                       int4* __restrict__ sdst,             // bf16 plane dest (or null)
                       float* __restrict__ out, int hop, int fb, int n_nodes) {
    int tid = blockIdx.x * blockDim.x + threadIdx.x;
    int l = tid & 3;
    int r = tid >> 2;
    if (r >= n_nodes) return;
    int c = cnt[r];
    if (c > ELLW) c = ELLW;
    float4 a0 = make_float4(0.f, 0.f, 0.f, 0.f);
    float4 a1 = make_float4(0.f, 0.f, 0.f, 0.f);
    int e = 0;
    for (; e + 2 <= c; e += 2) {
        float4 s = ell4[(size_t)r * (ELLW / 2) + (e >> 1)];   // (c0,v0,c1,v1)
        int i0 = __float_as_int(s.x) + l;
        int i1 = __float_as_int(s.z) + l;
        int4 g0 = ssrc[i0];
        int4 g1 = ssrc[i1];
        float v0 = s.y, v1 = s.w;
        a0.x += v0 * bflo(g0.x); a0.y += v0 * bfhi(g0.x);
        a0.z += v0 * bflo(g0.y); a0.w += v0 * bfhi(g0.y);
        a1.x += v0 * bflo(g0.z); a1.y += v0 * bfhi(g0.z);
        a1.z += v0 * bflo(g0.w); a1.w += v0 * bfhi(g0.w);
        a0.x += v1 * bflo(g1.x); a0.y += v1 * bfhi(g1.x);
        a0.z += v1 * bflo(g1.y); a0.w += v1 * bfhi(g1.y);
        a1.x += v1 * bflo(g1.z); a1.y += v1 * bfhi(g1.z);
        a1.z += v1 * bflo(g1.w); a1.w += v1 * bfhi(g1.w);
    }
    if (e < c) {
        float2 s = ((const float2*)ell4)[(size_t)r * ELLW + e];
        int i0 = __float_as_int(s.x) + l;
        int4 g0 = ssrc[i0];
        float v0 = s.y;
        a0.x += v0 * bflo(g0.x); a0.y += v0 * bfhi(g0.x);
        a0.z += v0 * bflo(g0.y); a0.w += v0 * bfhi(g0.y);
        a1.x += v0 * bflo(g0.z); a1.y += v0 * bfhi(g0.z);
        a1.z += v0 * bflo(g0.w); a1.w += v0 * bfhi(g0.w);
    }
    // d_out: quads r*64 + hop*16 + fb*8 + l*2 (feats fb*32+l*8 .. +8)
    size_t dq = (size_t)r * 64 + (size_t)hop * 16 + fb * 8 + l * 2;
    f32x4 n0 = {a0.x, a0.y, a0.z, a0.w};
    f32x4 n1 = {a1.x, a1.y, a1.z, a1.w};
    __builtin_nontemporal_store(n0, (f32x4*)((float4*)out) + dq);
    __builtin_nontemporal_store(n1, (f32x4*)((float4*)out) + dq + 1);
    if (sdst) {
        sdst[(size_t)r * 4 + l] = make_int4(pack2(a0.x, a0.y), pack2(a0.z, a0.w),
                                            pack2(a1.x, a1.y), pack2(a1.z, a1.w));
    }
}

// ---------- overflow fixup: wave per edge, atomic add on fp32 d_out ----------
__global__ void gc_ovf(const int* __restrict__ ovfcnt, const int4* __restrict__ ovf,
                       float* __restrict__ out, int hop) {
    int gtid = blockIdx.x * blockDim.x + threadIdx.x;
    int wave = gtid >> 6;
    int lane = gtid & 63;
    int nw = (gridDim.x * blockDim.x) >> 6;
    int cntv = *ovfcnt;
    size_t src_base = (size_t)(hop - 1) * 64 + lane;
    size_t dst_base = (size_t)hop * 64 + lane;
    for (int e = wave; e < cntv; e += nw) {
        int4 ed = ovf[e];
        float v = __int_as_float(ed.z);
        float x = out[(size_t)ed.y * 4 + src_base];   // ed.y = col<<6 (quad base)
        unsafeAtomicAdd(&out[(size_t)ed.x * 256 + dst_base], v * x);
    }
}

// ---------- shadow re-derive for overflow rows (both planes) ----------
__global__ void gc_sfix(const int* __restrict__ ovfcnt, const int4* __restrict__ ovf,
                        const float* __restrict__ out, char* __restrict__ shadow,
                        int hop, int n_nodes) {
    int cntv = *ovfcnt;
    int f = threadIdx.x;                       // 0..63
    unsigned short* pl = (unsigned short*)(shadow + (size_t)(f >> 5) * n_nodes * 64);
    for (int i = blockIdx.x; i < cntv; i += gridDim.x) {
        int r = ovf[i].x;
        float x = out[(size_t)r * 256 + (size_t)hop * 64 + f];
        pl[(size_t)r * 32 + (f & 31)] = (unsigned short)(bf16rne(x) >> 16);
    }
}

// ---------- Tier C fallback: atomic ----------
__global__ void gc_init_out_full(const float4* __restrict__ user4,
                                 const float4* __restrict__ item4,
                                 float4* __restrict__ out4,
                                 int n_users, int n_nodes) {
    int tid = blockIdx.x * blockDim.x + threadIdx.x;
    if (tid >= n_nodes * 16) return;
    int node = tid >> 4;
    int q = tid & 15;
    float4 v = (node < n_users) ? user4[(size_t)node * 16 + q]
                                : item4[(size_t)(node - n_users) * 16 + q];
    float4 z = make_float4(0.f, 0.f, 0.f, 0.f);
    float4* p = out4 + (size_t)node * 64 + q;
    p[0] = v; p[16] = z; p[32] = z; p[48] = z;
}

__global__ void gc_spmm_atomic(const int* __restrict__ adj_row,
                               const int* __restrict__ adj_col,
                               const float* __restrict__ adj_val,
                               float* __restrict__ out, int hop, int nnz) {
    long long tid = (long long)blockIdx.x * blockDim.x + threadIdx.x;
    int e = (int)(tid >> 6);
    int j = (int)(tid & 63);
    if (e >= nnz) return;
    int r = adj_row[e];
    int c = adj_col[e];
    float v = adj_val[e];
    float x = out[(size_t)c * 256 + (size_t)(hop - 1) * 64 + j];
    unsafeAtomicAdd(&out[(size_t)r * 256 + (size_t)hop * 64 + j], v * x);
}

extern "C" void kernel_launch(void* const* d_in, const int* in_sizes, int n_in,
                              void* d_out, int out_size, void* d_ws, size_t ws_size,
                              hipStream_t stream) {
    const float* user_embed = (const float*)d_in[0];
    const float* item_embed = (const float*)d_in[1];
    const int*   adj_row    = (const int*)d_in[2];
    const int*   adj_col    = (const int*)d_in[3];
    const float* adj_val    = (const float*)d_in[4];
    const int n_users = in_sizes[0] / DFEAT;
    const int n_items = in_sizes[1] / DFEAT;
    const int n_nodes = n_users + n_items;
    const int nnz     = in_sizes[2];
    float* out = (float*)d_out;
    float4* out4 = (float4*)out;

    const int threads = 256;
    const size_t plane_bytes = (size_t)n_nodes * 64;   // 32MB per feature plane

    // ---- workspace carve-up ----
    size_t off = 0;
    auto carve = [&](size_t bytes) { size_t o = off; off = (off + bytes + 255) & ~(size_t)255; return o; };
    size_t o_cnt    = carve((size_t)n_nodes * 4);
    size_t o_ovfcnt = carve(256);
    size_t zero_end = off;
    size_t o_ell    = carve((size_t)n_nodes * ELLW * 8);
    size_t o_ovf    = carve((size_t)nnz * 16);
    size_t o_shA    = carve(plane_bytes * 2);   // 64 MB (2 planes)
    size_t o_shB    = carve(plane_bytes * 2);   // 64 MB (2 planes)
    size_t needed = off;

    if (ws_size < needed) {
        // Tier C: atomic fallback.
        int init_blocks = (n_nodes * 16 + threads - 1) / threads;
        hipLaunchKernelGGL(gc_init_out_full, dim3(init_blocks), dim3(threads), 0, stream,
                           (const float4*)user_embed, (const float4*)item_embed,
                           out4, n_users, n_nodes);
        long long spmm_total = (long long)nnz * 64;
        int spmm_blocks = (int)((spmm_total + threads - 1) / threads);
        for (int h = 1; h <= 3; ++h) {
            hipLaunchKernelGGL(gc_spmm_atomic, dim3(spmm_blocks), dim3(threads), 0, stream,
                               adj_row, adj_col, adj_val, out, h, nnz);
        }
        return;
    }

    char* ws = (char*)d_ws;
    int*    cnt    = (int*)(ws + o_cnt);
    int*    ovfcnt = (int*)(ws + o_ovfcnt);
    float2* ell    = (float2*)(ws + o_ell);
    int4*   ovf    = (int4*)(ws + o_ovf);
    char*   shA    = ws + o_shA;
    char*   shB    = ws + o_shB;

    // ---- zero cnt + ovfcnt ----
    int zn4 = (int)((zero_end - o_cnt) / 16);
    int zero_blocks = (zn4 + threads - 1) / threads;
    hipLaunchKernelGGL(gc_zero, dim3(zero_blocks), dim3(threads), 0, stream,
                       (int4*)(ws + o_cnt), zn4);

    // ---- fat: init hop0 (NT d_out + shadowA planes) || ELL scatter ----
    int initB = (n_nodes * 16 + threads - 1) / threads;
    int scatB = (nnz + threads - 1) / threads;
    hipLaunchKernelGGL(gc_fat, dim3(initB + scatB), dim3(threads), 0, stream,
                       (const float4*)user_embed, (const float4*)item_embed,
                       out4, shA,
                       adj_row, adj_col, adj_val, cnt, ell, ovfcnt, ovf,
                       n_users, n_nodes, nnz, initB);

    // ---- 3 hops x 2 feature half-passes; shadow ping-pong; fixups ----
    long long hop_threads = (long long)n_nodes * 4;
    int hop_blocks = (int)((hop_threads + threads - 1) / threads);
    const int ovf_blocks = 256;
    char* scur = shA;
    char* snext = shB;
    for (int h = 1; h <= 3; ++h) {
        for (int fb = 0; fb < 2; ++fb) {
            const int4* ssrc = (const int4*)(scur + (size_t)fb * plane_bytes);
            int4* sdst = (h < 3) ? (int4*)(snext + (size_t)fb * plane_bytes)
                                 : (int4*)nullptr;
            hipLaunchKernelGGL(gc_hop, dim3(hop_blocks), dim3(threads), 0, stream,
                               cnt, (const float4*)ell, ssrc, sdst,
                               out, h, fb, n_nodes);
        }
        hipLaunchKernelGGL(gc_ovf, dim3(ovf_blocks), dim3(threads), 0, stream,
                           ovfcnt, ovf, out, h);
        if (h < 3) {
            hipLaunchKernelGGL(gc_sfix, dim3(256), dim3(64), 0, stream,
                               ovfcnt, ovf, out, snext, h, n_nodes);
            char* t = scur; scur = snext; snext = t;
        }
    }
}

// Round 13
// 329.578 us; speedup vs baseline: 1.2919x; 1.2919x over previous
//
#include <hip/hip_runtime.h>

// GraphConv 3-hop SpMM. R13 = R11 revert (best known, 327us) + fixup-grid trim.
//  - Every d_out slice write NONTEMPORAL (never re-read): 512MB pure stream.
//  - Hop h gathers from compact bf16 shadow [N,64] (64MB), writes fp32 d_out
//    slice + bf16 shadow for hop h+1.
//  - ELL(12)-direct build, fat kernel overlaps init with scatter.
//  - Overflow (deg>12, ~0 edges): atomic fp32 fixup + shadow row re-derive.
// d_out layout: [N_NODES, 4, 64] fp32.

#define DFEAT 64
#define ELLW 12

typedef float f32x4 __attribute__((ext_vector_type(4)));

__device__ inline unsigned bf16rne(float x) {           // bf16 in high 16 bits
    unsigned u = __float_as_uint(x);
    u += 0x7FFF + ((u >> 16) & 1);
    return u;
}
__device__ inline unsigned pack2(float lo, float hi) {  // [lo|hi] packed bf16x2
    return (bf16rne(lo) >> 16) | (bf16rne(hi) & 0xFFFF0000u);
}
__device__ inline float bflo(unsigned w) { return __uint_as_float(w << 16); }
__device__ inline float bfhi(unsigned w) { return __uint_as_float(w & 0xFFFF0000u); }

// ---------- zero cnt + ovfcnt ----------
__global__ void gc_zero(int4* __restrict__ p, int n4) {
    int i = blockIdx.x * blockDim.x + threadIdx.x;
    if (i < n4) p[i] = make_int4(0, 0, 0, 0);
}

// ---------- fat: blocks [0,initB) init hop0 (d_out NT + shadow0);
//             blocks [initB,..) ELL scatter ----------
__global__ void gc_fat(const float4* __restrict__ user4,
                       const float4* __restrict__ item4,
                       float4* __restrict__ out4, uint2* __restrict__ shadow0,
                       const int* __restrict__ row, const int* __restrict__ col,
                       const float* __restrict__ val,
                       int* __restrict__ cnt, float2* __restrict__ ell,
                       int* __restrict__ ovfcnt, int4* __restrict__ ovf,
                       int n_users, int n_nodes, int nnz, int initB) {
    int b = blockIdx.x;
    if (b < initB) {
        int tid = b * blockDim.x + threadIdx.x;
        if (tid >= n_nodes * 16) return;
        int node = tid >> 4;
        int q = tid & 15;
        float4 v = (node < n_users) ? user4[(size_t)node * 16 + q]
                                    : item4[(size_t)(node - n_users) * 16 + q];
        f32x4 nv = {v.x, v.y, v.z, v.w};
        __builtin_nontemporal_store(nv, (f32x4*)(out4 + (size_t)node * 64 + q));
        // 4 floats -> 4 bf16 = 8B = 1 uint2; 16 uint2 per node (128B/node).
        shadow0[(size_t)node * 16 + q] = make_uint2(pack2(v.x, v.y), pack2(v.z, v.w));
    } else {
        int i = (b - initB) * blockDim.x + threadIdx.x;
        if (i >= nnz) return;
        int r = row[i];
        int pos = atomicAdd(&cnt[r], 1);
        if (pos < ELLW) {
            // colcode = col*8 (int4 base index into 128B/node shadow)
            ell[(size_t)r * ELLW + pos] = make_float2(__int_as_float(col[i] << 3), val[i]);
        } else {
            int o = atomicAdd(ovfcnt, 1);
            ovf[o] = make_int4(r, col[i] << 6, __float_as_int(val[i]), 0);
        }
    }
}

// ---------- hop: 8 lanes per row (8 bf16 each), 8 rows/wave, unroll 2 ----------
__global__ void gc_hop(const int* __restrict__ cnt,
                       const float4* __restrict__ ell4,     // 2 slots per float4
                       const int4* __restrict__ ssrc,       // bf16 shadow source
                       int4* __restrict__ sdst,             // bf16 shadow dest (or null)
                       float* __restrict__ out, int hop, int n_nodes) {
    int tid = blockIdx.x * blockDim.x + threadIdx.x;
    int l = tid & 7;
    int r = tid >> 3;
    if (r >= n_nodes) return;
    int c = cnt[r];
    if (c > ELLW) c = ELLW;
    float4 a0 = make_float4(0.f, 0.f, 0.f, 0.f);
    float4 a1 = make_float4(0.f, 0.f, 0.f, 0.f);
    int e = 0;
    for (; e + 2 <= c; e += 2) {
        float4 s = ell4[(size_t)r * (ELLW / 2) + (e >> 1)];   // (c0,v0,c1,v1)
        int i0 = __float_as_int(s.x) + l;
        int i1 = __float_as_int(s.z) + l;
        int4 g0 = ssrc[i0];
        int4 g1 = ssrc[i1];
        float v0 = s.y, v1 = s.w;
        a0.x += v0 * bflo(g0.x); a0.y += v0 * bfhi(g0.x);
        a0.z += v0 * bflo(g0.y); a0.w += v0 * bfhi(g0.y);
        a1.x += v0 * bflo(g0.z); a1.y += v0 * bfhi(g0.z);
        a1.z += v0 * bflo(g0.w); a1.w += v0 * bfhi(g0.w);
        a0.x += v1 * bflo(g1.x); a0.y += v1 * bfhi(g1.x);
        a0.z += v1 * bflo(g1.y); a0.w += v1 * bfhi(g1.y);
        a1.x += v1 * bflo(g1.z); a1.y += v1 * bfhi(g1.z);
        a1.z += v1 * bflo(g1.w); a1.w += v1 * bfhi(g1.w);
    }
    if (e < c) {
        float2 s = ((const float2*)ell4)[(size_t)r * ELLW + e];
        int i0 = __float_as_int(s.x) + l;
        int4 g0 = ssrc[i0];
        float v0 = s.y;
        a0.x += v0 * bflo(g0.x); a0.y += v0 * bfhi(g0.x);
        a0.z += v0 * bflo(g0.y); a0.w += v0 * bfhi(g0.y);
        a1.x += v0 * bflo(g0.z); a1.y += v0 * bfhi(g0.z);
        a1.z += v0 * bflo(g0.w); a1.w += v0 * bfhi(g0.w);
    }
    size_t dq = (size_t)r * 64 + (size_t)hop * 16 + l * 2;
    f32x4 n0 = {a0.x, a0.y, a0.z, a0.w};
    f32x4 n1 = {a1.x, a1.y, a1.z, a1.w};
    __builtin_nontemporal_store(n0, (f32x4*)((float4*)out) + dq);
    __builtin_nontemporal_store(n1, (f32x4*)((float4*)out) + dq + 1);
    if (sdst) {
        sdst[(size_t)r * 8 + l] = make_int4(pack2(a0.x, a0.y), pack2(a0.z, a0.w),
                                            pack2(a1.x, a1.y), pack2(a1.z, a1.w));
    }
}

// ---------- overflow fixup: wave per edge, atomic add on fp32 d_out ----------
__global__ void gc_ovf(const int* __restrict__ ovfcnt, const int4* __restrict__ ovf,
                       float* __restrict__ out, int hop) {
    int gtid = blockIdx.x * blockDim.x + threadIdx.x;
    int wave = gtid >> 6;
    int lane = gtid & 63;
    int nw = (gridDim.x * blockDim.x) >> 6;
    int cntv = *ovfcnt;
    size_t src_base = (size_t)(hop - 1) * 64 + lane;
    size_t dst_base = (size_t)hop * 64 + lane;
    for (int e = wave; e < cntv; e += nw) {
        int4 ed = ovf[e];
        float v = __int_as_float(ed.z);
        float x = out[(size_t)ed.y * 4 + src_base];   // ed.y = col<<6 (quad base)
        unsafeAtomicAdd(&out[(size_t)ed.x * 256 + dst_base], v * x);
    }
}

// ---------- shadow re-derive for overflow rows ----------
__global__ void gc_sfix(const int* __restrict__ ovfcnt, const int4* __restrict__ ovf,
                        const float* __restrict__ out, unsigned short* __restrict__ shadow,
                        int hop) {
    int cntv = *ovfcnt;
    for (int i = blockIdx.x; i < cntv; i += gridDim.x) {
        int r = ovf[i].x;
        float x = out[(size_t)r * 256 + (size_t)hop * 64 + threadIdx.x];
        shadow[(size_t)r * 64 + threadIdx.x] = (unsigned short)(bf16rne(x) >> 16);
    }
}

// ---------- Tier C fallback: atomic ----------
__global__ void gc_init_out_full(const float4* __restrict__ user4,
                                 const float4* __restrict__ item4,
                                 float4* __restrict__ out4,
                                 int n_users, int n_nodes) {
    int tid = blockIdx.x * blockDim.x + threadIdx.x;
    if (tid >= n_nodes * 16) return;
    int node = tid >> 4;
    int q = tid & 15;
    float4 v = (node < n_users) ? user4[(size_t)node * 16 + q]
                                : item4[(size_t)(node - n_users) * 16 + q];
    float4 z = make_float4(0.f, 0.f, 0.f, 0.f);
    float4* p = out4 + (size_t)node * 64 + q;
    p[0] = v; p[16] = z; p[32] = z; p[48] = z;
}

__global__ void gc_spmm_atomic(const int* __restrict__ adj_row,
                               const int* __restrict__ adj_col,
                               const float* __restrict__ adj_val,
                               float* __restrict__ out, int hop, int nnz) {
    long long tid = (long long)blockIdx.x * blockDim.x + threadIdx.x;
    int e = (int)(tid >> 6);
    int j = (int)(tid & 63);
    if (e >= nnz) return;
    int r = adj_row[e];
    int c = adj_col[e];
    float v = adj_val[e];
    float x = out[(size_t)c * 256 + (size_t)(hop - 1) * 64 + j];
    unsafeAtomicAdd(&out[(size_t)r * 256 + (size_t)hop * 64 + j], v * x);
}

extern "C" void kernel_launch(void* const* d_in, const int* in_sizes, int n_in,
                              void* d_out, int out_size, void* d_ws, size_t ws_size,
                              hipStream_t stream) {
    const float* user_embed = (const float*)d_in[0];
    const float* item_embed = (const float*)d_in[1];
    const int*   adj_row    = (const int*)d_in[2];
    const int*   adj_col    = (const int*)d_in[3];
    const float* adj_val    = (const float*)d_in[4];
    const int n_users = in_sizes[0] / DFEAT;
    const int n_items = in_sizes[1] / DFEAT;
    const int n_nodes = n_users + n_items;
    const int nnz     = in_sizes[2];
    float* out = (float*)d_out;
    float4* out4 = (float4*)out;

    const int threads = 256;

    // ---- workspace carve-up ----
    size_t off = 0;
    auto carve = [&](size_t bytes) { size_t o = off; off = (off + bytes + 255) & ~(size_t)255; return o; };
    size_t o_cnt    = carve((size_t)n_nodes * 4);
    size_t o_ovfcnt = carve(256);
    size_t zero_end = off;
    size_t o_ell    = carve((size_t)n_nodes * ELLW * 8);
    size_t o_ovf    = carve((size_t)nnz * 16);
    size_t o_shA    = carve((size_t)n_nodes * DFEAT * 2);   // 64 MB bf16
    size_t o_shB    = carve((size_t)n_nodes * DFEAT * 2);   // 64 MB bf16
    size_t needed = off;

    if (ws_size < needed) {
        // Tier C: atomic fallback.
        int init_blocks = (n_nodes * 16 + threads - 1) / threads;
        hipLaunchKernelGGL(gc_init_out_full, dim3(init_blocks), dim3(threads), 0, stream,
                           (const float4*)user_embed, (const float4*)item_embed,
                           out4, n_users, n_nodes);
        long long spmm_total = (long long)nnz * 64;
        int spmm_blocks = (int)((spmm_total + threads - 1) / threads);
        for (int h = 1; h <= 3; ++h) {
            hipLaunchKernelGGL(gc_spmm_atomic, dim3(spmm_blocks), dim3(threads), 0, stream,
                               adj_row, adj_col, adj_val, out, h, nnz);
        }
        return;
    }

    char* ws = (char*)d_ws;
    int*    cnt    = (int*)(ws + o_cnt);
    int*    ovfcnt = (int*)(ws + o_ovfcnt);
    float2* ell    = (float2*)(ws + o_ell);
    int4*   ovf    = (int4*)(ws + o_ovf);
    char*   shA    = ws + o_shA;
    char*   shB    = ws + o_shB;

    // ---- zero cnt + ovfcnt ----
    int zn4 = (int)((zero_end - o_cnt) / 16);
    int zero_blocks = (zn4 + threads - 1) / threads;
    hipLaunchKernelGGL(gc_zero, dim3(zero_blocks), dim3(threads), 0, stream,
                       (int4*)(ws + o_cnt), zn4);

    // ---- fat: init hop0 (NT d_out + shadowA) || ELL scatter ----
    int initB = (n_nodes * 16 + threads - 1) / threads;
    int scatB = (nnz + threads - 1) / threads;
    hipLaunchKernelGGL(gc_fat, dim3(initB + scatB), dim3(threads), 0, stream,
                       (const float4*)user_embed, (const float4*)item_embed,
                       out4, (uint2*)shA,
                       adj_row, adj_col, adj_val, cnt, ell, ovfcnt, ovf,
                       n_users, n_nodes, nnz, initB);

    // ---- 3 hops: shadow ping-pong A->B->A; overflow + shadow fixups ----
    long long hop_threads = (long long)n_nodes * 8;
    int hop_blocks = (int)((hop_threads + threads - 1) / threads);
    const int ovf_blocks = 64;   // ~0 overflow edges expected; launch-cost only
    char* scur = shA;
    char* snext = shB;
    for (int h = 1; h <= 3; ++h) {
        int4* sdst = (h < 3) ? (int4*)snext : (int4*)nullptr;
        hipLaunchKernelGGL(gc_hop, dim3(hop_blocks), dim3(threads), 0, stream,
                           cnt, (const float4*)ell, (const int4*)scur, sdst,
                           out, h, n_nodes);
        hipLaunchKernelGGL(gc_ovf, dim3(ovf_blocks), dim3(threads), 0, stream,
                           ovfcnt, ovf, out, h);
        if (h < 3) {
            hipLaunchKernelGGL(gc_sfix, dim3(64), dim3(64), 0, stream,
                               ovfcnt, ovf, out, (unsigned short*)snext, h);
            char* t = scur; scur = snext; snext = t;
        }
    }
}